// Round 1
// baseline (117.485 us; speedup 1.0000x reference)
//
#include <hip/hip_runtime.h>
#include <math.h>

// Problem dims (fixed by setup_inputs): B=2, D=64, H=96, W=96, fp32.
#define BDIM 2
#define DDIM 64
#define HDIM 96
#define WDIM 96
#define HW   (HDIM * WDIM)          // 9216
#define DHW  (DDIM * HDIM * WDIM)   // 589824
#define NVOX (BDIM * DHW)           // 1179648

#define BIGF 1e10f
#define FINF 3.0e38f

// ---------------------------------------------------------------------------
// Kernel 1: init f_pos/f_neg from target and EDT pass along W (contiguous).
// 8 lines of 96 per block, 256 threads. Also zeroes the 4 accumulators.
// ---------------------------------------------------------------------------
__global__ __launch_bounds__(256) void edt_pass_w(const float* __restrict__ target,
                                                  float* __restrict__ fp,
                                                  float* __restrict__ fn,
                                                  float* __restrict__ acc) {
    __shared__ float sfp[8 * WDIM];
    __shared__ float sfn[8 * WDIM];
    const int tid  = threadIdx.x;
    const int base = blockIdx.x * (8 * WDIM);

    if (blockIdx.x == 0 && tid < 4) acc[tid] = 0.0f;  // consumed by kernel 3 (stream-ordered)

    for (int t = tid; t < 8 * WDIM; t += 256) {
        float tg = target[base + t];
        bool  m  = tg > 0.5f;
        sfp[t] = m ? BIGF : 0.0f;
        sfn[t] = m ? 0.0f : BIGF;
    }
    __syncthreads();

    for (int t = tid; t < 8 * WDIM; t += 256) {
        const int l = t / WDIM;
        const int i = t - l * WDIM;
        const float4* rp = (const float4*)&sfp[l * WDIM];
        const float4* rn = (const float4*)&sfn[l * WDIM];
        float mp = FINF, mn = FINF;
        float d0 = (float)i;  // d = i - j, j ascending
        #pragma unroll 6
        for (int j4 = 0; j4 < WDIM / 4; ++j4) {
            float4 p = rp[j4];
            float4 n = rn[j4];
            float d1 = d0 - 1.f, d2 = d0 - 2.f, d3 = d0 - 3.f;
            mp = fminf(mp, fmaf(d0, d0, p.x));
            mp = fminf(mp, fmaf(d1, d1, p.y));
            mp = fminf(mp, fmaf(d2, d2, p.z));
            mp = fminf(mp, fmaf(d3, d3, p.w));
            mn = fminf(mn, fmaf(d0, d0, n.x));
            mn = fminf(mn, fmaf(d1, d1, n.y));
            mn = fminf(mn, fmaf(d2, d2, n.z));
            mn = fminf(mn, fmaf(d3, d3, n.w));
            d0 -= 4.f;
        }
        fp[base + t] = mp;
        fn[base + t] = mn;
    }
}

// ---------------------------------------------------------------------------
// Kernel 2: EDT pass along H. Tile = one (b,d) slab x 96 h x 32 w.
// grid = B*D*3. In-place (tiles partition the array).
// ---------------------------------------------------------------------------
__global__ __launch_bounds__(256) void edt_pass_h(float* __restrict__ fp,
                                                  float* __restrict__ fn) {
    __shared__ float sfp[HDIM * 32];
    __shared__ float sfn[HDIM * 32];
    const int tid  = threadIdx.x;
    const int slab = blockIdx.x / 3;            // b*D + d
    const int w0   = (blockIdx.x % 3) * 32;
    const int base = slab * HW + w0;            // element (h, wi) -> base + h*W + wi

    for (int t = tid; t < HDIM * 32; t += 256) {
        int h = t >> 5, wi = t & 31;
        int g = base + h * WDIM + wi;
        sfp[t] = fp[g];
        sfn[t] = fn[g];
    }
    __syncthreads();

    for (int k = 0; k < 3; ++k) {
        int gq = tid + 256 * k;                 // [0, 768): 96 h x 8 float4 cols
        int ho = gq >> 3;
        int q  = gq & 7;
        float4 mp = {FINF, FINF, FINF, FINF};
        float4 mn = {FINF, FINF, FINF, FINF};
        float dcur = (float)ho;
        const float4* rp = ((const float4*)sfp) + q;
        const float4* rn = ((const float4*)sfn) + q;
        #pragma unroll 4
        for (int j = 0; j < HDIM; ++j) {
            float4 p = rp[j * 8];
            float4 n = rn[j * 8];
            float d2 = dcur * dcur;             // exact integer in f32
            mp.x = fminf(mp.x, d2 + p.x);
            mp.y = fminf(mp.y, d2 + p.y);
            mp.z = fminf(mp.z, d2 + p.z);
            mp.w = fminf(mp.w, d2 + p.w);
            mn.x = fminf(mn.x, d2 + n.x);
            mn.y = fminf(mn.y, d2 + n.y);
            mn.z = fminf(mn.z, d2 + n.z);
            mn.w = fminf(mn.w, d2 + n.w);
            dcur -= 1.f;
        }
        int g = base + ho * WDIM + q * 4;
        *(float4*)&fp[g] = mp;
        *(float4*)&fn[g] = mn;
    }
}

// ---------------------------------------------------------------------------
// Kernel 3: EDT pass along D + fused loss epilogue + per-batch reduction.
// Tile = one (b,h) x 64 d x 32 w. grid = B*H*3.
// ---------------------------------------------------------------------------
__device__ __forceinline__ void accum_loss(float mpv, float mnv, float p, float t,
                                           float& num, float& den) {
    float dp = sqrtf(mpv);
    float dn = sqrtf(mnv);
    float a  = fabsf(dn - dp);
    float w;
    if (a <= 3.0f)      w = 1.0f;
    else if (a >= 5.0f) w = 0.0f;
    else                w = 1.0f - (a - 3.0f) * 0.5f;
    float lp = fmaxf(logf(p), -100.0f);
    float l1 = fmaxf(logf(1.0f - p), -100.0f);
    float bce = -(t * lp + (1.0f - t) * l1);
    num += bce * w;
    den += w;
}

__global__ __launch_bounds__(256) void edt_pass_d_loss(const float* __restrict__ fp,
                                                       const float* __restrict__ fn,
                                                       const float* __restrict__ pred,
                                                       const float* __restrict__ target,
                                                       float* __restrict__ acc) {
    __shared__ float sfp[DDIM * 32];
    __shared__ float sfn[DDIM * 32];
    __shared__ float rsum[8];
    const int tid = threadIdx.x;
    const int w0  = (blockIdx.x % 3) * 32;
    const int bh  = blockIdx.x / 3;
    const int b   = bh / HDIM;
    const int h   = bh - b * HDIM;
    const int base = b * DHW + h * WDIM + w0;   // element (d, wi) -> base + d*HW + wi

    for (int t = tid; t < DDIM * 32; t += 256) {
        int d = t >> 5, wi = t & 31;
        int g = base + d * HW + wi;
        sfp[t] = fp[g];
        sfn[t] = fn[g];
    }
    __syncthreads();

    float num = 0.f, den = 0.f;
    for (int k = 0; k < 2; ++k) {
        int gq = tid + 256 * k;                 // [0, 512): 64 d x 8 float4 cols
        int dd = gq >> 3;
        int q  = gq & 7;
        float4 mp = {FINF, FINF, FINF, FINF};
        float4 mn = {FINF, FINF, FINF, FINF};
        float dcur = (float)dd;
        const float4* rp = ((const float4*)sfp) + q;
        const float4* rn = ((const float4*)sfn) + q;
        #pragma unroll 4
        for (int j = 0; j < DDIM; ++j) {
            float4 p = rp[j * 8];
            float4 n = rn[j * 8];
            float d2 = dcur * dcur;
            mp.x = fminf(mp.x, d2 + p.x);
            mp.y = fminf(mp.y, d2 + p.y);
            mp.z = fminf(mp.z, d2 + p.z);
            mp.w = fminf(mp.w, d2 + p.w);
            mn.x = fminf(mn.x, d2 + n.x);
            mn.y = fminf(mn.y, d2 + n.y);
            mn.z = fminf(mn.z, d2 + n.z);
            mn.w = fminf(mn.w, d2 + n.w);
            dcur -= 1.f;
        }
        int g = base + dd * HW + q * 4;
        float4 pr = *(const float4*)&pred[g];
        float4 tg = *(const float4*)&target[g];
        accum_loss(mp.x, mn.x, pr.x, tg.x, num, den);
        accum_loss(mp.y, mn.y, pr.y, tg.y, num, den);
        accum_loss(mp.z, mn.z, pr.z, tg.z, num, den);
        accum_loss(mp.w, mn.w, pr.w, tg.w, num, den);
    }

    // wave (64) reduce, then cross-wave via LDS, then one atomic pair per block
    for (int off = 32; off > 0; off >>= 1) {
        num += __shfl_down(num, off);
        den += __shfl_down(den, off);
    }
    if ((tid & 63) == 0) {
        rsum[tid >> 6]       = num;
        rsum[4 + (tid >> 6)] = den;
    }
    __syncthreads();
    if (tid == 0) {
        float ns = rsum[0] + rsum[1] + rsum[2] + rsum[3];
        float ds = rsum[4] + rsum[5] + rsum[6] + rsum[7];
        atomicAdd(&acc[b], ns);
        atomicAdd(&acc[2 + b], ds);
    }
}

// ---------------------------------------------------------------------------
// Kernel 4: finalize scalar
// ---------------------------------------------------------------------------
__global__ void finalize(const float* __restrict__ acc, float* __restrict__ out) {
    if (threadIdx.x == 0) {
        float r0 = acc[0] / (acc[2] + 1e-5f);
        float r1 = acc[1] / (acc[3] + 1e-5f);
        out[0] = 0.5f * (r0 + r1);
    }
}

extern "C" void kernel_launch(void* const* d_in, const int* in_sizes, int n_in,
                              void* d_out, int out_size, void* d_ws, size_t ws_size,
                              hipStream_t stream) {
    const float* pred   = (const float*)d_in[0];
    const float* target = (const float*)d_in[1];
    float* fp  = (float*)d_ws;          // NVOX floats
    float* fn  = fp + NVOX;             // NVOX floats
    float* acc = fn + NVOX;             // 4 floats: num[2], den[2]
    float* out = (float*)d_out;

    edt_pass_w<<<BDIM * DDIM * HDIM / 8, 256, 0, stream>>>(target, fp, fn, acc);
    edt_pass_h<<<BDIM * DDIM * 3, 256, 0, stream>>>(fp, fn);
    edt_pass_d_loss<<<BDIM * HDIM * 3, 256, 0, stream>>>(fp, fn, pred, target, acc);
    finalize<<<1, 64, 0, stream>>>(acc, out);
}